// Round 6
// baseline (264.603 us; speedup 1.0000x reference)
//
#include <hip/hip_runtime.h>
#include <math.h>

#define BB 32
#define TT 4096
#define DD 768
#define NH 4
#define RELW 32
#define NREL 65
#define HIDDEN 256
#define INPROJ 1792  // DD + NH*64 + DD

#define NSTR 128     // strips per batch (32 rows each)
#define SROWS 32
#define NSTEP 16     // 2 rows per step

// ---- wave64 sum via DPP (VALU pipe, no DS traffic) ----
template <int CTRL, int RMASK>
__device__ __forceinline__ float upd0(float x) {
    return __int_as_float(__builtin_amdgcn_update_dpp(
        0, __float_as_int(x), CTRL, RMASK, 0xf, true));
}
__device__ __forceinline__ float wave_sum64(float x) {
    x += upd0<0x111, 0xf>(x);   // row_shr:1
    x += upd0<0x112, 0xf>(x);   // row_shr:2
    x += upd0<0x114, 0xf>(x);   // row_shr:4
    x += upd0<0x118, 0xf>(x);   // row_shr:8
    x += upd0<0x142, 0xa>(x);   // row_bcast:15
    x += upd0<0x143, 0xc>(x);   // row_bcast:31 -> lane63 = total
    return __int_as_float(__builtin_amdgcn_readlane(__float_as_int(x), 63));
}

// ---------------- kA: h_i gather -> R[:,0:768], Q = h_i*WQ, qk = (Q*WK)/8 ----------------
__global__ __launch_bounds__(256) void kA(const float* __restrict__ H,
                                          const int* __restrict__ noun_pos,
                                          const float* __restrict__ WQ,
                                          const float* __restrict__ WK,
                                          float* __restrict__ R,
                                          float* __restrict__ qk_ws) {
    int b = blockIdx.x / NH, h = blockIdx.x % NH;
    __shared__ float hi_s[DD];
    __shared__ float q_s[64];
    int tn = noun_pos[b];
    const float* Hrow = H + ((size_t)b * TT + tn) * DD;
    for (int d = threadIdx.x; d < DD; d += 256) {
        float v = Hrow[d];
        hi_s[d] = v;
        if (h == 0) R[(size_t)b * INPROJ + d] = v;
    }
    __syncthreads();
    if (threadIdx.x < 64) {
        int k = threadIdx.x;
        const float* wq = WQ + (size_t)h * DD * 64 + k;
        float acc = 0.f;
        for (int d = 0; d < DD; ++d) acc += hi_s[d] * wq[(size_t)d * 64];
        q_s[k] = acc;
    }
    __syncthreads();
    for (int d = threadIdx.x; d < DD; d += 256) {
        const float* wk = WK + ((size_t)h * DD + d) * 64;
        float acc = 0.f;
        #pragma unroll
        for (int k = 0; k < 64; ++k) acc += q_s[k] * wk[k];
        qk_ws[((size_t)b * NH + h) * DD + d] = acc * 0.125f;  // 1/sqrt(64)
    }
}

// ---------------- kR: pooled -> R[:,1024:1792] ----------------
__global__ __launch_bounds__(256) void kR(const float* __restrict__ pooled,
                                          float* __restrict__ R) {
    int b = blockIdx.x / 3, seg = blockIdx.x % 3;
    int i = seg * 256 + threadIdx.x;
    R[(size_t)b * INPROJ + DD + NH * 64 + i] = pooled[(size_t)b * DD + i];
}

// ---------------- kFlash: 1 wave per 32-row strip, register-resident, DPP reduce ----------------
#define DOT(ACC, CV, QV) ACC += CV.x*QV.x + CV.y*QV.y + CV.z*QV.z + CV.w*QV.w

#define HUPD(M, L, S0, S1, B0, B1, B2)                                    \
  {                                                                        \
    float nm = fmaxf(M, fmaxf(S0, S1));                                    \
    if (nm > M + 8.0f) {                                                   \
      float sc = __expf(M - nm);                                           \
      L *= sc;                                                             \
      B0.x*=sc; B0.y*=sc; B0.z*=sc; B0.w*=sc;                              \
      B1.x*=sc; B1.y*=sc; B1.z*=sc; B1.w*=sc;                              \
      B2.x*=sc; B2.y*=sc; B2.z*=sc; B2.w*=sc;                              \
      M = nm;                                                              \
    }                                                                      \
    float p0 = __expf(S0 - M), p1 = __expf(S1 - M);                        \
    L += p0 + p1;                                                          \
    B0.x += p0*c0.x + p1*c3.x; B0.y += p0*c0.y + p1*c3.y;                  \
    B0.z += p0*c0.z + p1*c3.z; B0.w += p0*c0.w + p1*c3.w;                  \
    B1.x += p0*c1.x + p1*c4.x; B1.y += p0*c1.y + p1*c4.y;                  \
    B1.z += p0*c1.z + p1*c4.z; B1.w += p0*c1.w + p1*c4.w;                  \
    B2.x += p0*c2.x + p1*c5.x; B2.y += p0*c2.y + p1*c5.y;                  \
    B2.z += p0*c2.z + p1*c5.z; B2.w += p0*c2.w + p1*c5.w;                  \
  }

__global__ __launch_bounds__(64, 3) void kFlash(const float* __restrict__ H,
                                                const int* __restrict__ mask,
                                                const int* __restrict__ noun_pos,
                                                const float* __restrict__ rel_bias,
                                                const float* __restrict__ qk_ws,
                                                float* __restrict__ macc,
                                                float* __restrict__ ml) {
    const int g = blockIdx.x;
    const int b = g / NSTR, st = g % NSTR;
    const int lane = threadIdx.x;
    const int t0 = st * SROWS;
    const int tn = noun_pos[b];

    __shared__ float4 rbL[SROWS];   // mask-folded rel bias per strip row

    if (lane < SROWS) {
        int t = t0 + lane;
        int dl = t - tn; dl = dl < -RELW ? -RELW : (dl > RELW ? RELW : dl);
        float4 rv;
        if (mask[(size_t)b * TT + t]) {
            rv.x = rel_bias[0 * NREL + dl + RELW];
            rv.y = rel_bias[1 * NREL + dl + RELW];
            rv.z = rel_bias[2 * NREL + dl + RELW];
            rv.w = rel_bias[3 * NREL + dl + RELW];
        } else {
            rv.x = rv.y = rv.z = rv.w = -2.0e9f;
        }
        rbL[lane] = rv;
    }
    __syncthreads();

    float4 qr[NH][3];
    {
        const float4* qk4 = (const float4*)(qk_ws + (size_t)b * NH * DD);
        #pragma unroll
        for (int h = 0; h < NH; ++h)
            #pragma unroll
            for (int j = 0; j < 3; ++j)
                qr[h][j] = qk4[h * 192 + j * 64 + lane];
    }

    float m0 = -3.0e38f, m1 = -3.0e38f, m2 = -3.0e38f, m3 = -3.0e38f;
    float l0 = 0.f, l1 = 0.f, l2 = 0.f, l3 = 0.f;
    float4 A00{0,0,0,0}, A01{0,0,0,0}, A02{0,0,0,0};
    float4 A10{0,0,0,0}, A11{0,0,0,0}, A12{0,0,0,0};
    float4 A20{0,0,0,0}, A21{0,0,0,0}, A22{0,0,0,0};
    float4 A30{0,0,0,0}, A31{0,0,0,0}, A32{0,0,0,0};

    const float4* __restrict__ Hc = (const float4*)(H + ((size_t)b * TT + t0) * DD);

    float4 c0 = Hc[lane],        c1 = Hc[64 + lane],  c2 = Hc[128 + lane];
    float4 c3 = Hc[192 + lane],  c4 = Hc[256 + lane], c5 = Hc[320 + lane];
    float4 n0, n1, n2, n3, n4, n5;

    #pragma unroll 1
    for (int s = 0; s < NSTEP; ++s) {
        if (s + 1 < NSTEP) {
            const float4* Hn = Hc + (2 * s + 2) * 192;
            n0 = Hn[lane];       n1 = Hn[64 + lane];  n2 = Hn[128 + lane];
            n3 = Hn[192 + lane]; n4 = Hn[256 + lane]; n5 = Hn[320 + lane];
        }
        float s00 = 0, s01 = 0, s02 = 0, s03 = 0;
        float s10 = 0, s11 = 0, s12 = 0, s13 = 0;
        DOT(s00, c0, qr[0][0]); DOT(s00, c1, qr[0][1]); DOT(s00, c2, qr[0][2]);
        DOT(s01, c0, qr[1][0]); DOT(s01, c1, qr[1][1]); DOT(s01, c2, qr[1][2]);
        DOT(s02, c0, qr[2][0]); DOT(s02, c1, qr[2][1]); DOT(s02, c2, qr[2][2]);
        DOT(s03, c0, qr[3][0]); DOT(s03, c1, qr[3][1]); DOT(s03, c2, qr[3][2]);
        DOT(s10, c3, qr[0][0]); DOT(s10, c4, qr[0][1]); DOT(s10, c5, qr[0][2]);
        DOT(s11, c3, qr[1][0]); DOT(s11, c4, qr[1][1]); DOT(s11, c5, qr[1][2]);
        DOT(s12, c3, qr[2][0]); DOT(s12, c4, qr[2][1]); DOT(s12, c5, qr[2][2]);
        DOT(s13, c3, qr[3][0]); DOT(s13, c4, qr[3][1]); DOT(s13, c5, qr[3][2]);
        float r00 = wave_sum64(s00), r01 = wave_sum64(s01);
        float r02 = wave_sum64(s02), r03 = wave_sum64(s03);
        float r10 = wave_sum64(s10), r11 = wave_sum64(s11);
        float r12 = wave_sum64(s12), r13 = wave_sum64(s13);
        float4 rb0 = rbL[2 * s], rb1 = rbL[2 * s + 1];
        r00 += rb0.x; r01 += rb0.y; r02 += rb0.z; r03 += rb0.w;
        r10 += rb1.x; r11 += rb1.y; r12 += rb1.z; r13 += rb1.w;
        HUPD(m0, l0, r00, r10, A00, A01, A02);
        HUPD(m1, l1, r01, r11, A10, A11, A12);
        HUPD(m2, l2, r02, r12, A20, A21, A22);
        HUPD(m3, l3, r03, r13, A30, A31, A32);
        c0 = n0; c1 = n1; c2 = n2; c3 = n3; c4 = n4; c5 = n5;
    }

    float4* mo = (float4*)(macc + (size_t)g * NH * DD);
    mo[0 * 192 + 0 * 64 + lane] = A00; mo[0 * 192 + 64 + lane] = A01; mo[0 * 192 + 128 + lane] = A02;
    mo[1 * 192 + 0 * 64 + lane] = A10; mo[1 * 192 + 64 + lane] = A11; mo[1 * 192 + 128 + lane] = A12;
    mo[2 * 192 + 0 * 64 + lane] = A20; mo[2 * 192 + 64 + lane] = A21; mo[2 * 192 + 128 + lane] = A22;
    mo[3 * 192 + 0 * 64 + lane] = A30; mo[3 * 192 + 64 + lane] = A31; mo[3 * 192 + 128 + lane] = A32;
    if (lane == 0) {
        float* mp = ml + (size_t)g * NH * 2;
        mp[0] = m0; mp[1] = l0; mp[2] = m1; mp[3] = l1;
        mp[4] = m2; mp[5] = l2; mp[6] = m3; mp[7] = l3;
    }
}

// ---------------- kComb2: hbar[b,h,d] = (1/L) * sum_strips w_c * macc ----------------
__global__ __launch_bounds__(256) void kComb2(const float* __restrict__ macc,
                                              const float* __restrict__ ml,
                                              float* __restrict__ hbar) {
    int blk = blockIdx.x;
    int b = blk / 12, rem = blk % 12, h = rem / 3, dseg = rem % 3;
    int d = dseg * 256 + threadIdx.x;
    const float* mlb = ml + (size_t)b * NSTR * 8 + h * 2;
    float M = -3.0e38f;
    #pragma unroll 8
    for (int c = 0; c < NSTR; ++c) M = fmaxf(M, mlb[(size_t)c * 8]);
    float L = 0.f;
    #pragma unroll 8
    for (int c = 0; c < NSTR; ++c)
        L += __expf(mlb[(size_t)c * 8] - M) * mlb[(size_t)c * 8 + 1];
    float acc = 0.f;
    const float* mc = macc + ((size_t)b * NSTR * NH + h) * DD + d;
    #pragma unroll 8
    for (int c = 0; c < NSTR; ++c)
        acc += __expf(mlb[(size_t)c * 8] - M) * mc[(size_t)c * NH * DD];
    hbar[((size_t)b * NH + h) * DD + d] = acc / L;
}

// ---------------- kC2: c[b,h,v] = hbar[b,h,:]*WV[h,:,v] -> R[:,768:1024] ----------------
__global__ __launch_bounds__(64) void kC2(const float* __restrict__ hbar,
                                          const float* __restrict__ WV,
                                          float* __restrict__ R) {
    int b = blockIdx.x / NH, h = blockIdx.x % NH;
    int v = threadIdx.x;
    const float* hb = hbar + ((size_t)b * NH + h) * DD;
    const float* wv = WV + (size_t)h * DD * 64 + v;
    float acc = 0.f;
    #pragma unroll 8
    for (int d = 0; d < DD; ++d) acc += hb[d] * wv[(size_t)d * 64];
    R[(size_t)b * INPROJ + DD + h * 64 + v] = acc;
}

// ---------------- kT: transpose proj_w ----------------
__global__ __launch_bounds__(256) void kT(const float* __restrict__ pw,
                                          float* __restrict__ pwT) {
    int o = blockIdx.x * 256 + threadIdx.x;
    int j = o / INPROJ, i = o % INPROJ;
    pwT[(size_t)i * HIDDEN + j] = pw[o];
}

// ---------------- kH: hdn = GELU(R*pwT + pb); logits ----------------
__global__ __launch_bounds__(256) void kH(const float* __restrict__ R,
                                          const float* __restrict__ pwT,
                                          const float* __restrict__ pb,
                                          const float* __restrict__ mw,
                                          const float* __restrict__ mb,
                                          float* __restrict__ out) {
    int b = blockIdx.x;
    int j = threadIdx.x;
    __shared__ float r_s[INPROJ];
    __shared__ float hdn_s[HIDDEN];
    for (int i = j; i < INPROJ; i += 256) r_s[i] = R[(size_t)b * INPROJ + i];
    __syncthreads();
    float acc = pb[j];
    #pragma unroll 16
    for (int i = 0; i < INPROJ; ++i) acc += r_s[i] * pwT[(size_t)i * HIDDEN + j];
    hdn_s[j] = 0.5f * acc * (1.f + erff(acc * 0.70710678118654752f));
    __syncthreads();
    float p0 = hdn_s[j] * mw[j];
    float p1 = hdn_s[j] * mw[HIDDEN + j];
    #pragma unroll
    for (int off = 32; off; off >>= 1) {
        p0 += __shfl_xor(p0, off);
        p1 += __shfl_xor(p1, off);
    }
    __shared__ float r0[4], r1[4];
    if ((j & 63) == 0) {
        r0[j >> 6] = p0;
        r1[j >> 6] = p1;
    }
    __syncthreads();
    if (j == 0) {
        out[b * 2 + 0] = r0[0] + r0[1] + r0[2] + r0[3] + mb[0];
        out[b * 2 + 1] = r1[0] + r1[1] + r1[2] + r1[3] + mb[1];
    }
}

extern "C" void kernel_launch(void* const* d_in, const int* in_sizes, int n_in,
                              void* d_out, int out_size, void* d_ws, size_t ws_size,
                              hipStream_t stream) {
    const float* H      = (const float*)d_in[0];
    const int*   mask   = (const int*)d_in[1];
    const int*   noun   = (const int*)d_in[2];
    const float* pooled = (const float*)d_in[3];
    const float* WQ     = (const float*)d_in[4];
    const float* WK     = (const float*)d_in[5];
    const float* WV     = (const float*)d_in[6];
    const float* relb   = (const float*)d_in[7];
    const float* pw     = (const float*)d_in[8];
    const float* pb     = (const float*)d_in[9];
    const float* mw     = (const float*)d_in[10];
    const float* mb     = (const float*)d_in[11];
    float* out = (float*)d_out;

    float* ws   = (float*)d_ws;
    float* R    = ws;                                 // BB*INPROJ      = 57344
    float* qk   = R + (size_t)BB * INPROJ;            // BB*NH*DD       = 98304
    float* macc = qk + (size_t)BB * NH * DD;          // BB*NSTR*NH*DD  = 12582912
    float* ml   = macc + (size_t)BB * NSTR * NH * DD; // BB*NSTR*NH*2   = 32768
    float* hbar = ml + (size_t)BB * NSTR * NH * 2;    // BB*NH*DD       = 98304
    float* pwT  = hbar + (size_t)BB * NH * DD;        // INPROJ*HIDDEN  = 458752

    kA<<<BB * NH, 256, 0, stream>>>(H, noun, WQ, WK, R, qk);
    kR<<<BB * 3, 256, 0, stream>>>(pooled, R);
    kFlash<<<BB * NSTR, 64, 0, stream>>>(H, mask, noun, relb, qk, macc, ml);
    kComb2<<<BB * 12, 256, 0, stream>>>(macc, ml, hbar);
    kC2<<<BB * NH, 64, 0, stream>>>(hbar, WV, R);
    kT<<<(HIDDEN * INPROJ) / 256, 256, 0, stream>>>(pw, pwT);
    kH<<<BB, 256, 0, stream>>>(R, pwT, pb, mw, mb, out);
}

// Round 7
// 241.540 us; speedup vs baseline: 1.0955x; 1.0955x over previous
//
#include <hip/hip_runtime.h>
#include <math.h>

#define BB 32
#define TT 4096
#define DD 768
#define NH 4
#define RELW 32
#define NREL 65
#define HIDDEN 256
#define INPROJ 1792  // DD + NH*64 + DD

#define NCH 32
#define CROWS (TT / NCH)       // 128 rows per chunk (block)
#define TROWS 8                // rows per LDS tile
#define NT (CROWS / TROWS)     // 16 tiles
#define C4 (DD / 4)            // 192 float4 per row

#define BARRIER() __builtin_amdgcn_s_barrier()
#define FENCE_LGKM() asm volatile("s_waitcnt lgkmcnt(0)" ::: "memory")
#define WAITVM6() asm volatile("s_waitcnt vmcnt(6)" ::: "memory")
#define WAITVM0() asm volatile("s_waitcnt vmcnt(0)" ::: "memory")

__device__ __forceinline__ void gl_lds16(const float* g, float* l) {
    __builtin_amdgcn_global_load_lds(
        (const __attribute__((address_space(1))) float*)(uintptr_t)g,
        (__attribute__((address_space(3))) float*)(uintptr_t)l,
        16, 0, 0);
}

// ---------------- kernel A: h_i gather, Q = h_i*WQ, qk = (Q*WK)/8 ----------------
__global__ __launch_bounds__(256) void kA(const float* __restrict__ H,
                                          const int* __restrict__ noun_pos,
                                          const float* __restrict__ WQ,
                                          const float* __restrict__ WK,
                                          float* __restrict__ hi_ws,
                                          float* __restrict__ qk_ws) {
    int b = blockIdx.x / NH, h = blockIdx.x % NH;
    __shared__ float hi_s[DD];
    __shared__ float q_s[64];
    int tn = noun_pos[b];
    const float* Hrow = H + ((size_t)b * TT + tn) * DD;
    for (int d = threadIdx.x; d < DD; d += 256) {
        float v = Hrow[d];
        hi_s[d] = v;
        if (h == 0) hi_ws[b * DD + d] = v;
    }
    __syncthreads();
    if (threadIdx.x < 64) {
        int k = threadIdx.x;
        const float* wq = WQ + (size_t)h * DD * 64 + k;
        float acc = 0.f;
        for (int d = 0; d < DD; ++d) acc += hi_s[d] * wq[(size_t)d * 64];
        q_s[k] = acc;
    }
    __syncthreads();
    for (int d = threadIdx.x; d < DD; d += 256) {
        const float* wk = WK + ((size_t)h * DD + d) * 64;
        float acc = 0.f;
        #pragma unroll
        for (int k = 0; k < 64; ++k) acc += q_s[k] * wk[k];
        qk_ws[((size_t)b * NH + h) * DD + d] = acc * 0.125f;  // 1/sqrt(64)
    }
}

// ---------------- kFlash: single pass over H, async dbuf, online softmax ----------------
__global__ __launch_bounds__(256, 2) void kFlash(const float* __restrict__ H,
                                                 const int* __restrict__ mask,
                                                 const int* __restrict__ noun_pos,
                                                 const float* __restrict__ rel_bias,
                                                 const float* __restrict__ qk_ws,
                                                 float* __restrict__ macc,
                                                 float* __restrict__ ml) {
    const int b   = blockIdx.x / NCH;
    const int ch  = blockIdx.x % NCH;
    const int tid = threadIdx.x;
    const int wave = tid >> 6, lane = tid & 63;
    const int sl = lane >> 2, hh = lane & 3;   // 16 d-slices x 4 heads

    __shared__ float4 Hts[2][TROWS * C4];      // 2 x 24 KB double buffer
    __shared__ float4 rbL[CROWS];              // mask-folded rel bias per chunk row
    __shared__ __align__(16) float sL[TROWS * NH];

    const int t0 = ch * CROWS;
    const int tn = noun_pos[b];

    // fold mask + rel_bias for this chunk's rows
    if (tid < CROWS) {
        int t = t0 + tid;
        int dl = t - tn; dl = dl < -RELW ? -RELW : (dl > RELW ? RELW : dl);
        int mm = mask[(size_t)b * TT + t];
        float4 rv;
        if (mm) {
            rv.x = rel_bias[0 * NREL + dl + RELW];
            rv.y = rel_bias[1 * NREL + dl + RELW];
            rv.z = rel_bias[2 * NREL + dl + RELW];
            rv.w = rel_bias[3 * NREL + dl + RELW];
        } else {
            rv.x = rv.y = rv.z = rv.w = -2.0e9f;
        }
        rbL[tid] = rv;
    }

    // qk fragment: head hh, d-positions {16j + sl}*4
    float4 qkr[12];
    {
        const float4* qk4 = (const float4*)(qk_ws + ((size_t)b * NH + hh) * DD);
        #pragma unroll
        for (int j = 0; j < 12; ++j) qkr[j] = qk4[j * 16 + sl];
    }

    float m0 = -3.0e38f, m1 = -3.0e38f, m2 = -3.0e38f, m3 = -3.0e38f;
    float l0 = 0.f, l1 = 0.f, l2 = 0.f, l3 = 0.f;
    float4 a0 = {0.f,0.f,0.f,0.f}, a1 = {0.f,0.f,0.f,0.f};
    float4 a2 = {0.f,0.f,0.f,0.f}, a3 = {0.f,0.f,0.f,0.f};

    const float* Hc = H + ((size_t)b * TT + t0) * DD;

    __syncthreads();   // rbL visible; vm drained -> clean vmcnt slate

    // prologue: stage tile 0 into buf 0 (6 insts/wave, 1KB each)
    {
        float* dst = (float*)&Hts[0][0];
        #pragma unroll
        for (int i = 0; i < 6; ++i) {
            int base = (wave * 6 + i) * 256;
            gl_lds16(Hc + base + lane * 4, dst + base);
        }
    }

    #pragma unroll 1
    for (int t = 0; t < NT; ++t) {
        const int cur = t & 1;
        // stage tile t+1 into other buffer; keep its 6 loads in flight
        if (t + 1 < NT) {
            const float* src = Hc + (size_t)(t + 1) * TROWS * DD;
            float* dst = (float*)&Hts[cur ^ 1][0];
            #pragma unroll
            for (int i = 0; i < 6; ++i) {
                int base = (wave * 6 + i) * 256;
                gl_lds16(src + base + lane * 4, dst + base);
            }
            WAITVM6();   // tile t's 6 loads complete; t+1's stay in flight
        } else {
            WAITVM0();
        }
        BARRIER();       // A: tile t resident for all waves

        const float4* Htc = &Hts[cur][0];
        // scores: wave handles rows 2w, 2w+1; 4 head-lanes share each read (broadcast)
        #pragma unroll
        for (int k = 0; k < 2; ++k) {
            const int r = wave * 2 + k;
            const float4* Hr = Htc + r * C4;
            float acc = 0.f;
            #pragma unroll
            for (int j = 0; j < 12; ++j) {
                float4 hv = Hr[j * 16 + sl];
                acc += hv.x * qkr[j].x + hv.y * qkr[j].y + hv.z * qkr[j].z + hv.w * qkr[j].w;
            }
            acc += __shfl_xor(acc, 4);
            acc += __shfl_xor(acc, 8);
            acc += __shfl_xor(acc, 16);
            acc += __shfl_xor(acc, 32);
            if (lane < NH)
                sL[r * NH + lane] = acc + ((const float*)&rbL[t * TROWS + r])[lane];
        }
        FENCE_LGKM();
        BARRIER();       // B: sL visible

        // online softmax, redundant per-thread (reads sL as 8 broadcast b128)
        float4 p4[TROWS];
        {
            const float4* sL4 = (const float4*)sL;
            #pragma unroll
            for (int r = 0; r < TROWS; ++r) p4[r] = sL4[r];
            float tx = p4[0].x, ty = p4[0].y, tz = p4[0].z, tw = p4[0].w;
            #pragma unroll
            for (int r = 1; r < TROWS; ++r) {
                tx = fmaxf(tx, p4[r].x); ty = fmaxf(ty, p4[r].y);
                tz = fmaxf(tz, p4[r].z); tw = fmaxf(tw, p4[r].w);
            }
            float n0 = fmaxf(m0, tx), n1 = fmaxf(m1, ty);
            float n2 = fmaxf(m2, tz), n3 = fmaxf(m3, tw);
            float s0 = __expf(m0 - n0), s1 = __expf(m1 - n1);
            float s2 = __expf(m2 - n2), s3 = __expf(m3 - n3);
            float q0 = 0.f, q1 = 0.f, q2 = 0.f, q3 = 0.f;
            #pragma unroll
            for (int r = 0; r < TROWS; ++r) {
                p4[r].x = __expf(p4[r].x - n0); q0 += p4[r].x;
                p4[r].y = __expf(p4[r].y - n1); q1 += p4[r].y;
                p4[r].z = __expf(p4[r].z - n2); q2 += p4[r].z;
                p4[r].w = __expf(p4[r].w - n3); q3 += p4[r].w;
            }
            l0 = l0 * s0 + q0; l1 = l1 * s1 + q1;
            l2 = l2 * s2 + q2; l3 = l3 * s3 + q3;
            m0 = n0; m1 = n1; m2 = n2; m3 = n3;
            a0.x *= s0; a0.y *= s0; a0.z *= s0; a0.w *= s0;
            a1.x *= s1; a1.y *= s1; a1.z *= s1; a1.w *= s1;
            a2.x *= s2; a2.y *= s2; a2.z *= s2; a2.w *= s2;
            a3.x *= s3; a3.y *= s3; a3.z *= s3; a3.w *= s3;
        }
        // accumulate: thread owns float4 column tid (192 active)
        if (tid < C4) {
            #pragma unroll
            for (int r = 0; r < TROWS; ++r) {
                float4 hv = Htc[r * C4 + tid];
                a0.x += p4[r].x * hv.x; a0.y += p4[r].x * hv.y; a0.z += p4[r].x * hv.z; a0.w += p4[r].x * hv.w;
                a1.x += p4[r].y * hv.x; a1.y += p4[r].y * hv.y; a1.z += p4[r].y * hv.z; a1.w += p4[r].y * hv.w;
                a2.x += p4[r].z * hv.x; a2.y += p4[r].z * hv.y; a2.z += p4[r].z * hv.z; a2.w += p4[r].z * hv.w;
                a3.x += p4[r].w * hv.x; a3.y += p4[r].w * hv.y; a3.z += p4[r].w * hv.z; a3.w += p4[r].w * hv.w;
            }
        }
        FENCE_LGKM();
        BARRIER();       // D: all reads drained; buffers/sL reusable
    }

    if (tid < C4) {
        float4* mo = (float4*)(macc + (size_t)blockIdx.x * NH * DD);
        mo[0 * C4 + tid] = a0;
        mo[1 * C4 + tid] = a1;
        mo[2 * C4 + tid] = a2;
        mo[3 * C4 + tid] = a3;
    }
    if (tid == 0) {
        float* mp = ml + (size_t)blockIdx.x * NH * 2;
        mp[0] = m0; mp[1] = l0; mp[2] = m1; mp[3] = l1;
        mp[4] = m2; mp[5] = l2; mp[6] = m3; mp[7] = l3;
    }
}

// ---------------- transpose proj_w (HIDDEN,INPROJ) -> (INPROJ,HIDDEN) ----------------
__global__ __launch_bounds__(256) void kT(const float* __restrict__ pw,
                                          float* __restrict__ pwT) {
    int o = blockIdx.x * 256 + threadIdx.x;
    int j = o / INPROJ, i = o % INPROJ;
    pwT[(size_t)i * HIDDEN + j] = pw[o];
}

// ---------------- kD: flash-combine + c = hbar*WV + concat + GELU MLP + logits ----------------
__global__ __launch_bounds__(256) void kD(const float* __restrict__ macc,
                                          const float* __restrict__ ml,
                                          const float* __restrict__ hi_ws,
                                          const float* __restrict__ pooled,
                                          const float* __restrict__ WV,
                                          const float* __restrict__ pwT,
                                          const float* __restrict__ pb,
                                          const float* __restrict__ mw,
                                          const float* __restrict__ mb,
                                          float* __restrict__ out) {
    int b = blockIdx.x;
    __shared__ float w_s[NCH][NH];
    __shared__ float invL_s[NH];
    __shared__ float hb_s[NH * DD];
    __shared__ float r_s[INPROJ];
    __shared__ float hdn_s[HIDDEN];

    if (threadIdx.x < NH) {
        int h = threadIdx.x;
        float M = -3.0e38f;
        for (int c = 0; c < NCH; ++c)
            M = fmaxf(M, ml[((b * NCH + c) * NH + h) * 2 + 0]);
        float L = 0.f;
        for (int c = 0; c < NCH; ++c) {
            float w = __expf(ml[((b * NCH + c) * NH + h) * 2 + 0] - M);
            w_s[c][h] = w;
            L += w * ml[((b * NCH + c) * NH + h) * 2 + 1];
        }
        invL_s[h] = 1.f / L;
    }
    for (int i = threadIdx.x; i < DD; i += 256) {
        r_s[i] = hi_ws[b * DD + i];
        r_s[DD + NH * 64 + i] = pooled[b * DD + i];
    }
    __syncthreads();
    for (int i = threadIdx.x; i < NH * DD; i += 256) {
        int h = i / DD, d = i % DD;
        float a = 0.f;
        #pragma unroll
        for (int c = 0; c < NCH; ++c)
            a += w_s[c][h] * macc[((size_t)(b * NCH + c) * NH + h) * DD + d];
        hb_s[i] = a * invL_s[h];
    }
    __syncthreads();
    {
        int h = threadIdx.x >> 6, v = threadIdx.x & 63;
        const float* wv = WV + (size_t)h * DD * 64 + v;
        const float* hb = hb_s + h * DD;
        float acc = 0.f;
        for (int d = 0; d < DD; ++d) acc += hb[d] * wv[(size_t)d * 64];
        r_s[DD + threadIdx.x] = acc;
    }
    __syncthreads();
    {
        int j = threadIdx.x;
        float acc = pb[j];
        #pragma unroll 8
        for (int i = 0; i < INPROJ; ++i) acc += r_s[i] * pwT[(size_t)i * HIDDEN + j];
        hdn_s[j] = 0.5f * acc * (1.f + erff(acc * 0.70710678118654752f));
    }
    __syncthreads();
    float p0 = hdn_s[threadIdx.x] * mw[threadIdx.x];
    float p1 = hdn_s[threadIdx.x] * mw[HIDDEN + threadIdx.x];
    #pragma unroll
    for (int off = 32; off; off >>= 1) {
        p0 += __shfl_xor(p0, off);
        p1 += __shfl_xor(p1, off);
    }
    __shared__ float r0[4], r1[4];
    if ((threadIdx.x & 63) == 0) {
        r0[threadIdx.x >> 6] = p0;
        r1[threadIdx.x >> 6] = p1;
    }
    __syncthreads();
    if (threadIdx.x == 0) {
        out[b * 2 + 0] = r0[0] + r0[1] + r0[2] + r0[3] + mb[0];
        out[b * 2 + 1] = r1[0] + r1[1] + r1[2] + r1[3] + mb[1];
    }
}

extern "C" void kernel_launch(void* const* d_in, const int* in_sizes, int n_in,
                              void* d_out, int out_size, void* d_ws, size_t ws_size,
                              hipStream_t stream) {
    const float* H      = (const float*)d_in[0];
    const int*   mask   = (const int*)d_in[1];
    const int*   noun   = (const int*)d_in[2];
    const float* pooled = (const float*)d_in[3];
    const float* WQ     = (const float*)d_in[4];
    const float* WK     = (const float*)d_in[5];
    const float* WV     = (const float*)d_in[6];
    const float* relb   = (const float*)d_in[7];
    const float* pw     = (const float*)d_in[8];
    const float* pb     = (const float*)d_in[9];
    const float* mw     = (const float*)d_in[10];
    const float* mb     = (const float*)d_in[11];
    float* out = (float*)d_out;

    float* ws   = (float*)d_ws;
    float* hi   = ws;                               // BB*DD         = 24576
    float* qk   = hi + BB * DD;                     // BB*NH*DD      = 98304
    float* macc = qk + BB * NH * DD;                // BB*NCH*NH*DD  = 3145728
    float* ml   = macc + (size_t)BB * NCH * NH * DD;// BB*NCH*NH*2   = 8192
    float* pwT  = ml + BB * NCH * NH * 2;           // INPROJ*HIDDEN = 458752

    kA<<<BB * NH, 256, 0, stream>>>(H, noun, WQ, WK, hi, qk);
    kFlash<<<BB * NCH, 256, 0, stream>>>(H, mask, noun, relb, qk, macc, ml);
    kT<<<(HIDDEN * INPROJ) / 256, 256, 0, stream>>>(pw, pwT);
    kD<<<BB, 256, 0, stream>>>(macc, ml, hi, pooled, WV, pwT, pb, mw, mb, out);
}

// Round 8
// 188.728 us; speedup vs baseline: 1.4020x; 1.2798x over previous
//
#include <hip/hip_runtime.h>
#include <math.h>

#define BB 32
#define TT 4096
#define DD 768
#define NH 4
#define RELW 32
#define NREL 65
#define HIDDEN 256
#define INPROJ 1792  // DD + NH*64 + DD

#define NCH 32
#define CROWS (TT / NCH)       // 128 rows per chunk (block)
#define TROWS 8                // rows per LDS tile
#define NT (CROWS / TROWS)     // 16 tiles max
#define C4 (DD / 4)            // 192 float4 per row

#define BARRIER() __builtin_amdgcn_s_barrier()
#define FENCE_LGKM() asm volatile("s_waitcnt lgkmcnt(0)" ::: "memory")
#define WAITVM6() asm volatile("s_waitcnt vmcnt(6)" ::: "memory")
#define WAITVM0() asm volatile("s_waitcnt vmcnt(0)" ::: "memory")

__device__ __forceinline__ void gl_lds16(const float* g, float* l) {
    __builtin_amdgcn_global_load_lds(
        (const __attribute__((address_space(1))) float*)(uintptr_t)g,
        (__attribute__((address_space(3))) float*)(uintptr_t)l,
        16, 0, 0);
}

// ---------------- kA: h_i gather -> R[:,0:768] & hi, Q = h_i*WQ, qk = (Q*WK)/8 ----------------
__global__ __launch_bounds__(256) void kA(const float* __restrict__ H,
                                          const int* __restrict__ noun_pos,
                                          const float* __restrict__ WQ,
                                          const float* __restrict__ WK,
                                          float* __restrict__ R,
                                          float* __restrict__ qk_ws) {
    int b = blockIdx.x / NH, h = blockIdx.x % NH;
    __shared__ float hi_s[DD];
    __shared__ float q_s[64];
    int tn = noun_pos[b];
    const float* Hrow = H + ((size_t)b * TT + tn) * DD;
    for (int d = threadIdx.x; d < DD; d += 256) {
        float v = Hrow[d];
        hi_s[d] = v;
        if (h == 0) R[(size_t)b * INPROJ + d] = v;
    }
    __syncthreads();
    if (threadIdx.x < 64) {
        int k = threadIdx.x;
        const float* wq = WQ + (size_t)h * DD * 64 + k;
        float acc = 0.f;
        for (int d = 0; d < DD; ++d) acc += hi_s[d] * wq[(size_t)d * 64];
        q_s[k] = acc;
    }
    __syncthreads();
    for (int d = threadIdx.x; d < DD; d += 256) {
        const float* wk = WK + ((size_t)h * DD + d) * 64;
        float acc = 0.f;
        #pragma unroll
        for (int k = 0; k < 64; ++k) acc += q_s[k] * wk[k];
        qk_ws[((size_t)b * NH + h) * DD + d] = acc * 0.125f;  // 1/sqrt(64)
    }
}

// ---------------- kFlash: single pass over valid H rows, async dbuf, online softmax ----------------
__global__ __launch_bounds__(256, 2) void kFlash(const float* __restrict__ H,
                                                 const int* __restrict__ mask,
                                                 const int* __restrict__ noun_pos,
                                                 const float* __restrict__ rel_bias,
                                                 const float* __restrict__ qk_ws,
                                                 float* __restrict__ macc,
                                                 float* __restrict__ ml) {
    const int b   = blockIdx.x / NCH;
    const int ch  = blockIdx.x % NCH;
    const int tid = threadIdx.x;
    const int wave = tid >> 6, lane = tid & 63;
    const int sl = lane >> 2, hh = lane & 3;   // 16 d-slices x 4 heads

    __shared__ float4 Hts[2][TROWS * C4];      // 2 x 24 KB double buffer
    __shared__ float4 rbL[CROWS];              // mask-folded rel bias per chunk row
    __shared__ __align__(16) float sL[TROWS * NH];
    __shared__ int snl;

    const int t0 = ch * CROWS;
    const int tn = noun_pos[b];

    if (tid == 0) snl = 0;
    __syncthreads();

    // fold mask + rel_bias; track last valid row (no monotonicity assumed)
    if (tid < CROWS) {
        int t = t0 + tid;
        int dl = t - tn; dl = dl < -RELW ? -RELW : (dl > RELW ? RELW : dl);
        int mm = mask[(size_t)b * TT + t];
        float4 rv;
        if (mm) {
            rv.x = rel_bias[0 * NREL + dl + RELW];
            rv.y = rel_bias[1 * NREL + dl + RELW];
            rv.z = rel_bias[2 * NREL + dl + RELW];
            rv.w = rel_bias[3 * NREL + dl + RELW];
            atomicMax(&snl, tid + 1);
        } else {
            rv.x = rv.y = rv.z = rv.w = -2.0e9f;
        }
        rbL[tid] = rv;
    }

    // qk fragment: head hh, d-positions {16j + sl}*4
    float4 qkr[12];
    {
        const float4* qk4 = (const float4*)(qk_ws + ((size_t)b * NH + hh) * DD);
        #pragma unroll
        for (int j = 0; j < 12; ++j) qkr[j] = qk4[j * 16 + sl];
    }

    __syncthreads();   // rbL/snl visible; compiler drains vmcnt -> clean slate
    const int NTE = (snl + TROWS - 1) / TROWS;   // tiles actually needed

    if (NTE == 0) {    // fully masked chunk: zero contribution
        float4 z = {0.f, 0.f, 0.f, 0.f};
        if (tid < C4) {
            float4* mo = (float4*)(macc + (size_t)blockIdx.x * NH * DD);
            mo[0 * C4 + tid] = z; mo[1 * C4 + tid] = z;
            mo[2 * C4 + tid] = z; mo[3 * C4 + tid] = z;
        }
        if (tid == 0) {
            float* mp = ml + (size_t)blockIdx.x * NH * 2;
            mp[0] = -3.0e38f; mp[1] = 0.f; mp[2] = -3.0e38f; mp[3] = 0.f;
            mp[4] = -3.0e38f; mp[5] = 0.f; mp[6] = -3.0e38f; mp[7] = 0.f;
        }
        return;
    }

    float m0 = -3.0e38f, m1 = -3.0e38f, m2 = -3.0e38f, m3 = -3.0e38f;
    float l0 = 0.f, l1 = 0.f, l2 = 0.f, l3 = 0.f;
    float4 a0 = {0.f,0.f,0.f,0.f}, a1 = {0.f,0.f,0.f,0.f};
    float4 a2 = {0.f,0.f,0.f,0.f}, a3 = {0.f,0.f,0.f,0.f};

    const float* Hc = H + ((size_t)b * TT + t0) * DD;

    // prologue: stage tile 0 into buf 0 (6 insts/wave, 1KB each)
    {
        float* dst = (float*)&Hts[0][0];
        #pragma unroll
        for (int i = 0; i < 6; ++i) {
            int base = (wave * 6 + i) * 256;
            gl_lds16(Hc + base + lane * 4, dst + base);
        }
    }

    #pragma unroll 1
    for (int t = 0; t < NTE; ++t) {
        const int cur = t & 1;
        if (t + 1 < NTE) {
            const float* src = Hc + (size_t)(t + 1) * TROWS * DD;
            float* dst = (float*)&Hts[cur ^ 1][0];
            #pragma unroll
            for (int i = 0; i < 6; ++i) {
                int base = (wave * 6 + i) * 256;
                gl_lds16(src + base + lane * 4, dst + base);
            }
            WAITVM6();   // tile t's 6 loads complete; t+1's stay in flight
        } else {
            WAITVM0();
        }
        BARRIER();       // A: tile t resident

        const float4* Htc = &Hts[cur][0];
        #pragma unroll
        for (int k = 0; k < 2; ++k) {
            const int r = wave * 2 + k;
            const float4* Hr = Htc + r * C4;
            float acc = 0.f;
            #pragma unroll
            for (int j = 0; j < 12; ++j) {
                float4 hv = Hr[j * 16 + sl];
                acc += hv.x * qkr[j].x + hv.y * qkr[j].y + hv.z * qkr[j].z + hv.w * qkr[j].w;
            }
            acc += __shfl_xor(acc, 4);
            acc += __shfl_xor(acc, 8);
            acc += __shfl_xor(acc, 16);
            acc += __shfl_xor(acc, 32);
            if (lane < NH)
                sL[r * NH + lane] = acc + ((const float*)&rbL[t * TROWS + r])[lane];
        }
        FENCE_LGKM();
        BARRIER();       // B: sL visible

        float4 p4[TROWS];
        {
            const float4* sL4 = (const float4*)sL;
            #pragma unroll
            for (int r = 0; r < TROWS; ++r) p4[r] = sL4[r];
            float tx = p4[0].x, ty = p4[0].y, tz = p4[0].z, tw = p4[0].w;
            #pragma unroll
            for (int r = 1; r < TROWS; ++r) {
                tx = fmaxf(tx, p4[r].x); ty = fmaxf(ty, p4[r].y);
                tz = fmaxf(tz, p4[r].z); tw = fmaxf(tw, p4[r].w);
            }
            float n0 = fmaxf(m0, tx), n1 = fmaxf(m1, ty);
            float n2 = fmaxf(m2, tz), n3 = fmaxf(m3, tw);
            float s0 = __expf(m0 - n0), s1 = __expf(m1 - n1);
            float s2 = __expf(m2 - n2), s3 = __expf(m3 - n3);
            float q0 = 0.f, q1 = 0.f, q2 = 0.f, q3 = 0.f;
            #pragma unroll
            for (int r = 0; r < TROWS; ++r) {
                p4[r].x = __expf(p4[r].x - n0); q0 += p4[r].x;
                p4[r].y = __expf(p4[r].y - n1); q1 += p4[r].y;
                p4[r].z = __expf(p4[r].z - n2); q2 += p4[r].z;
                p4[r].w = __expf(p4[r].w - n3); q3 += p4[r].w;
            }
            l0 = l0 * s0 + q0; l1 = l1 * s1 + q1;
            l2 = l2 * s2 + q2; l3 = l3 * s3 + q3;
            m0 = n0; m1 = n1; m2 = n2; m3 = n3;
            a0.x *= s0; a0.y *= s0; a0.z *= s0; a0.w *= s0;
            a1.x *= s1; a1.y *= s1; a1.z *= s1; a1.w *= s1;
            a2.x *= s2; a2.y *= s2; a2.z *= s2; a2.w *= s2;
            a3.x *= s3; a3.y *= s3; a3.z *= s3; a3.w *= s3;
        }
        if (tid < C4) {
            #pragma unroll
            for (int r = 0; r < TROWS; ++r) {
                float4 hv = Htc[r * C4 + tid];
                a0.x += p4[r].x * hv.x; a0.y += p4[r].x * hv.y; a0.z += p4[r].x * hv.z; a0.w += p4[r].x * hv.w;
                a1.x += p4[r].y * hv.x; a1.y += p4[r].y * hv.y; a1.z += p4[r].y * hv.z; a1.w += p4[r].y * hv.w;
                a2.x += p4[r].z * hv.x; a2.y += p4[r].z * hv.y; a2.z += p4[r].z * hv.z; a2.w += p4[r].z * hv.w;
                a3.x += p4[r].w * hv.x; a3.y += p4[r].w * hv.y; a3.z += p4[r].w * hv.z; a3.w += p4[r].w * hv.w;
            }
        }
        FENCE_LGKM();
        BARRIER();       // D: all reads drained; buffers reusable
    }

    if (tid < C4) {
        float4* mo = (float4*)(macc + (size_t)blockIdx.x * NH * DD);
        mo[0 * C4 + tid] = a0;
        mo[1 * C4 + tid] = a1;
        mo[2 * C4 + tid] = a2;
        mo[3 * C4 + tid] = a3;
    }
    if (tid == 0) {
        float* mp = ml + (size_t)blockIdx.x * NH * 2;
        mp[0] = m0; mp[1] = l0; mp[2] = m1; mp[3] = l1;
        mp[4] = m2; mp[5] = l2; mp[6] = m3; mp[7] = l3;
    }
}

// ---------------- kT: transpose proj_w (HIDDEN,INPROJ) -> (INPROJ,HIDDEN) ----------------
__global__ __launch_bounds__(256) void kT(const float* __restrict__ pw,
                                          float* __restrict__ pwT) {
    int o = blockIdx.x * 256 + threadIdx.x;
    int j = o / INPROJ, i = o % INPROJ;
    pwT[(size_t)i * HIDDEN + j] = pw[o];
}

// ---------------- kComb: hbar[b,h,d] = (1/L) * sum_ch w_ch * macc (wide: 384 blocks) ----------------
__global__ __launch_bounds__(256) void kComb(const float* __restrict__ macc,
                                             const float* __restrict__ ml,
                                             float* __restrict__ hbar) {
    int blk = blockIdx.x;
    int b = blk / 12, rem = blk % 12, h = rem / 3, dseg = rem % 3;
    int d = dseg * 256 + threadIdx.x;
    const float* mlb = ml + (size_t)b * NCH * 8 + h * 2;
    float M = -3.0e38f;
    #pragma unroll 8
    for (int c = 0; c < NCH; ++c) M = fmaxf(M, mlb[(size_t)c * 8]);
    float L = 0.f;
    #pragma unroll 8
    for (int c = 0; c < NCH; ++c)
        L += __expf(mlb[(size_t)c * 8] - M) * mlb[(size_t)c * 8 + 1];
    float acc = 0.f;
    const float* mc = macc + ((size_t)b * NCH * NH + h) * DD + d;
    #pragma unroll 8
    for (int c = 0; c < NCH; ++c)
        acc += __expf(mlb[(size_t)c * 8] - M) * mc[(size_t)c * NH * DD];
    hbar[((size_t)b * NH + h) * DD + d] = acc / L;
}

// ---------------- kC2: c = hbar*WV -> R[:,768:1024]; pooled -> R[:,1024:] ----------------
__global__ __launch_bounds__(256) void kC2(const float* __restrict__ hbar,
                                           const float* __restrict__ WV,
                                           const float* __restrict__ pooled,
                                           float* __restrict__ R) {
    int b = blockIdx.x;
    int h = threadIdx.x >> 6, v = threadIdx.x & 63;
    const float* hb = hbar + ((size_t)b * NH + h) * DD;
    const float* wv = WV + (size_t)h * DD * 64 + v;
    float acc = 0.f;
    #pragma unroll 8
    for (int d = 0; d < DD; ++d) acc += hb[d] * wv[(size_t)d * 64];
    R[(size_t)b * INPROJ + DD + threadIdx.x] = acc;
    for (int i = threadIdx.x; i < DD; i += 256)
        R[(size_t)b * INPROJ + DD + 256 + i] = pooled[(size_t)b * DD + i];
}

// ---------------- kH1: partial hidden GEMM, 7-way split over INPROJ ----------------
__global__ __launch_bounds__(256) void kH1(const float* __restrict__ R,
                                           const float* __restrict__ pwT,
                                           float* __restrict__ part2) {
    int b = blockIdx.x / 7, seg = blockIdx.x % 7;
    int j = threadIdx.x;
    __shared__ float r_s[256];
    r_s[j] = R[(size_t)b * INPROJ + seg * 256 + j];
    __syncthreads();
    float acc = 0.f;
    const float* pT = pwT + (size_t)seg * 256 * HIDDEN + j;
    #pragma unroll 8
    for (int i = 0; i < 256; ++i) acc += r_s[i] * pT[(size_t)i * HIDDEN];
    part2[((size_t)b * 7 + seg) * HIDDEN + j] = acc;
}

// ---------------- kH2: reduce partials + GELU + logits ----------------
__global__ __launch_bounds__(256) void kH2(const float* __restrict__ part2,
                                           const float* __restrict__ pb,
                                           const float* __restrict__ mw,
                                           const float* __restrict__ mb,
                                           float* __restrict__ out) {
    int b = blockIdx.x, j = threadIdx.x;
    float acc = pb[j];
    #pragma unroll
    for (int s = 0; s < 7; ++s) acc += part2[((size_t)b * 7 + s) * HIDDEN + j];
    float hdn = 0.5f * acc * (1.f + erff(acc * 0.70710678118654752f));
    float p0 = hdn * mw[j];
    float p1 = hdn * mw[HIDDEN + j];
    #pragma unroll
    for (int off = 32; off; off >>= 1) {
        p0 += __shfl_xor(p0, off);
        p1 += __shfl_xor(p1, off);
    }
    __shared__ float r0[4], r1[4];
    if ((j & 63) == 0) {
        r0[j >> 6] = p0;
        r1[j >> 6] = p1;
    }
    __syncthreads();
    if (j == 0) {
        out[b * 2 + 0] = r0[0] + r0[1] + r0[2] + r0[3] + mb[0];
        out[b * 2 + 1] = r1[0] + r1[1] + r1[2] + r1[3] + mb[1];
    }
}

extern "C" void kernel_launch(void* const* d_in, const int* in_sizes, int n_in,
                              void* d_out, int out_size, void* d_ws, size_t ws_size,
                              hipStream_t stream) {
    const float* H      = (const float*)d_in[0];
    const int*   mask   = (const int*)d_in[1];
    const int*   noun   = (const int*)d_in[2];
    const float* pooled = (const float*)d_in[3];
    const float* WQ     = (const float*)d_in[4];
    const float* WK     = (const float*)d_in[5];
    const float* WV     = (const float*)d_in[6];
    const float* relb   = (const float*)d_in[7];
    const float* pw     = (const float*)d_in[8];
    const float* pb     = (const float*)d_in[9];
    const float* mw     = (const float*)d_in[10];
    const float* mb     = (const float*)d_in[11];
    float* out = (float*)d_out;

    float* ws    = (float*)d_ws;
    float* R     = ws;                                // BB*INPROJ     = 57344
    float* qk    = R + (size_t)BB * INPROJ;           // BB*NH*DD      = 98304
    float* macc  = qk + (size_t)BB * NH * DD;         // BB*NCH*NH*DD  = 3145728
    float* ml    = macc + (size_t)BB * NCH * NH * DD; // BB*NCH*NH*2   = 8192
    float* hbar  = ml + (size_t)BB * NCH * NH * 2;    // BB*NH*DD      = 98304
    float* pwT   = hbar + (size_t)BB * NH * DD;       // INPROJ*HIDDEN = 458752
    float* part2 = pwT + (size_t)INPROJ * HIDDEN;     // BB*7*HIDDEN   = 57344

    kA<<<BB * NH, 256, 0, stream>>>(H, noun, WQ, WK, R, qk);
    kT<<<(HIDDEN * INPROJ) / 256, 256, 0, stream>>>(pw, pwT);
    kFlash<<<BB * NCH, 256, 0, stream>>>(H, mask, noun, relb, qk, macc, ml);
    kComb<<<BB * 12, 256, 0, stream>>>(macc, ml, hbar);
    kC2<<<BB, 256, 0, stream>>>(hbar, WV, pooled, R);
    kH1<<<BB * 7, 256, 0, stream>>>(R, pwT, part2);
    kH2<<<BB, 256, 0, stream>>>(part2, pb, mw, mb, out);
}

// Round 9
// 152.610 us; speedup vs baseline: 1.7338x; 1.2367x over previous
//
#include <hip/hip_runtime.h>
#include <math.h>

#define BB 32
#define TT 4096
#define DD 768
#define NH 4
#define RELW 32
#define NREL 65
#define HIDDEN 256
#define INPROJ 1792  // DD + NH*64 + DD

#define NCH 32
#define CROWS (TT / NCH)       // 128 rows per chunk (block)
#define TROWS 8                // rows per tile (2 per wave)
#define C4 (DD / 4)            // 192 float4 per row

#define WAITVM6() asm volatile("s_waitcnt vmcnt(6)" ::: "memory")
#define WAITVM0() asm volatile("s_waitcnt vmcnt(0)" ::: "memory")

__device__ __forceinline__ void gl_lds16(const float* g, float* l) {
    __builtin_amdgcn_global_load_lds(
        (const __attribute__((address_space(1))) float*)(uintptr_t)g,
        (__attribute__((address_space(3))) float*)(uintptr_t)l,
        16, 0, 0);
}

// ---- wave64 sum via DPP (VALU pipe, validated in R5: absmax 0.0) ----
template <int CTRL, int RMASK>
__device__ __forceinline__ float upd0(float x) {
    return __int_as_float(__builtin_amdgcn_update_dpp(
        0, __float_as_int(x), CTRL, RMASK, 0xf, true));
}
__device__ __forceinline__ float wave_sum64(float x) {
    x += upd0<0x111, 0xf>(x);   // row_shr:1
    x += upd0<0x112, 0xf>(x);   // row_shr:2
    x += upd0<0x114, 0xf>(x);   // row_shr:4
    x += upd0<0x118, 0xf>(x);   // row_shr:8
    x += upd0<0x142, 0xa>(x);   // row_bcast:15
    x += upd0<0x143, 0xc>(x);   // row_bcast:31 -> lane63 = total
    return __int_as_float(__builtin_amdgcn_readlane(__float_as_int(x), 63));
}

// ---------------- kA: h_i gather -> R[:,0:768], Q = h_i*WQ, qk = (Q*WK)/8 ----------------
__global__ __launch_bounds__(256) void kA(const float* __restrict__ H,
                                          const int* __restrict__ noun_pos,
                                          const float* __restrict__ WQ,
                                          const float* __restrict__ WK,
                                          float* __restrict__ R,
                                          float* __restrict__ qk_ws) {
    int b = blockIdx.x / NH, h = blockIdx.x % NH;
    __shared__ float hi_s[DD];
    __shared__ float q_s[64];
    int tn = noun_pos[b];
    const float* Hrow = H + ((size_t)b * TT + tn) * DD;
    for (int d = threadIdx.x; d < DD; d += 256) {
        float v = Hrow[d];
        hi_s[d] = v;
        if (h == 0) R[(size_t)b * INPROJ + d] = v;
    }
    __syncthreads();
    if (threadIdx.x < 64) {
        int k = threadIdx.x;
        const float* wq = WQ + (size_t)h * DD * 64 + k;
        float acc = 0.f;
        for (int d = 0; d < DD; ++d) acc += hi_s[d] * wq[(size_t)d * 64];
        q_s[k] = acc;
    }
    __syncthreads();
    for (int d = threadIdx.x; d < DD; d += 256) {
        const float* wk = WK + ((size_t)h * DD + d) * 64;
        float acc = 0.f;
        #pragma unroll
        for (int k = 0; k < 64; ++k) acc += q_s[k] * wk[k];
        qk_ws[((size_t)b * NH + h) * DD + d] = acc * 0.125f;  // 1/sqrt(64)
    }
}

// ---------------- kFlash: wave-independent pipelines, no in-loop barriers ----------------
#define DOT(ACC, CV, QV) ACC += CV.x*QV.x + CV.y*QV.y + CV.z*QV.z + CV.w*QV.w

#define HUPD(M, L, S0, S1, B0, B1, B2)                                    \
  {                                                                        \
    float nm = fmaxf(M, fmaxf(S0, S1));                                    \
    if (nm > M + 8.0f) {                                                   \
      float sc = __expf(M - nm);                                           \
      L *= sc;                                                             \
      B0.x*=sc; B0.y*=sc; B0.z*=sc; B0.w*=sc;                              \
      B1.x*=sc; B1.y*=sc; B1.z*=sc; B1.w*=sc;                              \
      B2.x*=sc; B2.y*=sc; B2.z*=sc; B2.w*=sc;                              \
      M = nm;                                                              \
    }                                                                      \
    float p0 = __expf(S0 - M), p1 = __expf(S1 - M);                        \
    L += p0 + p1;                                                          \
    B0.x += p0*c0.x + p1*c3.x; B0.y += p0*c0.y + p1*c3.y;                  \
    B0.z += p0*c0.z + p1*c3.z; B0.w += p0*c0.w + p1*c3.w;                  \
    B1.x += p0*c1.x + p1*c4.x; B1.y += p0*c1.y + p1*c4.y;                  \
    B1.z += p0*c1.z + p1*c4.z; B1.w += p0*c1.w + p1*c4.w;                  \
    B2.x += p0*c2.x + p1*c5.x; B2.y += p0*c2.y + p1*c5.y;                  \
    B2.z += p0*c2.z + p1*c5.z; B2.w += p0*c2.w + p1*c5.w;                  \
  }

__global__ __launch_bounds__(256, 3) void kFlash(const float* __restrict__ H,
                                                 const int* __restrict__ mask,
                                                 const int* __restrict__ noun_pos,
                                                 const float* __restrict__ rel_bias,
                                                 const float* __restrict__ qk_ws,
                                                 float* __restrict__ macc,
                                                 float* __restrict__ ml) {
    const int b   = blockIdx.x / NCH;
    const int ch  = blockIdx.x % NCH;
    const int tid = threadIdx.x;
    const int wave = tid >> 6, lane = tid & 63;

    __shared__ float4 Hts[2][TROWS * C4];   // 48 KB: dbuf; reused as combine scratch
    __shared__ float4 rbL[CROWS];           // 2 KB
    __shared__ float mls[4][8];
    __shared__ int snl;

    const int t0 = ch * CROWS;
    const int tn = noun_pos[b];

    if (tid == 0) snl = 0;
    __syncthreads();
    if (tid < CROWS) {
        int t = t0 + tid;
        int dl = t - tn; dl = dl < -RELW ? -RELW : (dl > RELW ? RELW : dl);
        int mm = mask[(size_t)b * TT + t];
        float4 rv;
        if (mm) {
            rv.x = rel_bias[0 * NREL + dl + RELW];
            rv.y = rel_bias[1 * NREL + dl + RELW];
            rv.z = rel_bias[2 * NREL + dl + RELW];
            rv.w = rel_bias[3 * NREL + dl + RELW];
            atomicMax(&snl, tid + 1);
        } else {
            rv.x = rv.y = rv.z = rv.w = -2.0e9f;
        }
        rbL[tid] = rv;
    }

    // qk fragment: lane's columns {j*64+lane}, all 4 heads (48 VGPR)
    float4 qr[NH][3];
    {
        const float4* qk4 = (const float4*)(qk_ws + (size_t)b * NH * DD);
        #pragma unroll
        for (int h = 0; h < NH; ++h)
            #pragma unroll
            for (int j = 0; j < 3; ++j)
                qr[h][j] = qk4[h * C4 + j * 64 + lane];
    }

    __syncthreads();
    const int NTE = (snl + TROWS - 1) / TROWS;

    if (NTE == 0) {
        float4 z = {0.f, 0.f, 0.f, 0.f};
        float4* mo = (float4*)(macc + (size_t)blockIdx.x * NH * DD);
        int h = tid >> 6, ln = tid & 63;
        #pragma unroll
        for (int j = 0; j < 3; ++j) mo[h * C4 + j * 64 + ln] = z;
        if (tid < NH) {
            float* mp = ml + (size_t)blockIdx.x * NH * 2;
            mp[tid * 2 + 0] = -3.0e38f; mp[tid * 2 + 1] = 0.f;
        }
        return;
    }

    float m0 = -3.0e38f, m1 = -3.0e38f, m2 = -3.0e38f, m3 = -3.0e38f;
    float l0 = 0.f, l1 = 0.f, l2 = 0.f, l3 = 0.f;
    float4 A00{0,0,0,0}, A01{0,0,0,0}, A02{0,0,0,0};
    float4 A10{0,0,0,0}, A11{0,0,0,0}, A12{0,0,0,0};
    float4 A20{0,0,0,0}, A21{0,0,0,0}, A22{0,0,0,0};
    float4 A30{0,0,0,0}, A31{0,0,0,0}, A32{0,0,0,0};

    const float* Hc = H + ((size_t)b * TT + t0) * DD;
    const int woff = wave * 1536;   // wave's 2 rows = 6 KB = 1536 floats

    // prologue: wave stages ITS rows of tile 0
    {
        float* dst = (float*)&Hts[0][0] + woff;
        const float* src = Hc + woff;
        #pragma unroll
        for (int i = 0; i < 6; ++i)
            gl_lds16(src + i * 256 + lane * 4, dst + i * 256);
    }

    #pragma unroll 1
    for (int t = 0; t < NTE; ++t) {
        const int cur = t & 1;
        if (t + 1 < NTE) {   // stage own rows of tile t+1 (per-wave, no barrier)
            float* dst = (float*)&Hts[cur ^ 1][0] + woff;
            const float* src = Hc + (size_t)(t + 1) * TROWS * DD + woff;
            #pragma unroll
            for (int i = 0; i < 6; ++i)
                gl_lds16(src + i * 256 + lane * 4, dst + i * 256);
            WAITVM6();       // own tile-t loads complete; t+1's stay in flight
        } else {
            WAITVM0();
        }
        // read own 2 rows once; lanes hold their accumulate columns
        const float4* Hr = &Hts[cur][0] + wave * 384;
        float4 c0 = Hr[lane],       c1 = Hr[64 + lane],  c2 = Hr[128 + lane];
        float4 c3 = Hr[192 + lane], c4 = Hr[256 + lane], c5 = Hr[320 + lane];

        float s00 = 0, s01 = 0, s02 = 0, s03 = 0;
        float s10 = 0, s11 = 0, s12 = 0, s13 = 0;
        DOT(s00, c0, qr[0][0]); DOT(s00, c1, qr[0][1]); DOT(s00, c2, qr[0][2]);
        DOT(s01, c0, qr[1][0]); DOT(s01, c1, qr[1][1]); DOT(s01, c2, qr[1][2]);
        DOT(s02, c0, qr[2][0]); DOT(s02, c1, qr[2][1]); DOT(s02, c2, qr[2][2]);
        DOT(s03, c0, qr[3][0]); DOT(s03, c1, qr[3][1]); DOT(s03, c2, qr[3][2]);
        DOT(s10, c3, qr[0][0]); DOT(s10, c4, qr[0][1]); DOT(s10, c5, qr[0][2]);
        DOT(s11, c3, qr[1][0]); DOT(s11, c4, qr[1][1]); DOT(s11, c5, qr[1][2]);
        DOT(s12, c3, qr[2][0]); DOT(s12, c4, qr[2][1]); DOT(s12, c5, qr[2][2]);
        DOT(s13, c3, qr[3][0]); DOT(s13, c4, qr[3][1]); DOT(s13, c5, qr[3][2]);
        float r00 = wave_sum64(s00), r01 = wave_sum64(s01);
        float r02 = wave_sum64(s02), r03 = wave_sum64(s03);
        float r10 = wave_sum64(s10), r11 = wave_sum64(s11);
        float r12 = wave_sum64(s12), r13 = wave_sum64(s13);
        float4 rb0 = rbL[t * TROWS + 2 * wave];
        float4 rb1 = rbL[t * TROWS + 2 * wave + 1];
        r00 += rb0.x; r01 += rb0.y; r02 += rb0.z; r03 += rb0.w;
        r10 += rb1.x; r11 += rb1.y; r12 += rb1.z; r13 += rb1.w;
        HUPD(m0, l0, r00, r10, A00, A01, A02);
        HUPD(m1, l1, r01, r11, A10, A11, A12);
        HUPD(m2, l2, r02, r12, A20, A21, A22);
        HUPD(m3, l3, r03, r13, A30, A31, A32);
    }

    // ---- in-block 4-wave flash combine (Hts reused as 48KB scratch) ----
    __syncthreads();   // all waves done with Hts data
    float4* scr = &Hts[0][0];  // [w][h][192] float4 = 3072 float4 = 48KB
    #pragma unroll
    for (int j = 0; j < 3; ++j) {
        scr[(wave * 4 + 0) * C4 + j * 64 + lane] = j == 0 ? A00 : (j == 1 ? A01 : A02);
        scr[(wave * 4 + 1) * C4 + j * 64 + lane] = j == 0 ? A10 : (j == 1 ? A11 : A12);
        scr[(wave * 4 + 2) * C4 + j * 64 + lane] = j == 0 ? A20 : (j == 1 ? A21 : A22);
        scr[(wave * 4 + 3) * C4 + j * 64 + lane] = j == 0 ? A30 : (j == 1 ? A31 : A32);
    }
    if (lane == 0) {
        mls[wave][0] = m0; mls[wave][1] = l0; mls[wave][2] = m1; mls[wave][3] = l1;
        mls[wave][4] = m2; mls[wave][5] = l2; mls[wave][6] = m3; mls[wave][7] = l3;
    }
    __syncthreads();
    {
        int h = tid >> 6, ln = tid & 63;
        float M = fmaxf(fmaxf(mls[0][h*2], mls[1][h*2]), fmaxf(mls[2][h*2], mls[3][h*2]));
        float w0 = __expf(mls[0][h*2] - M), w1 = __expf(mls[1][h*2] - M);
        float w2 = __expf(mls[2][h*2] - M), w3 = __expf(mls[3][h*2] - M);
        float4* mo = (float4*)(macc + (size_t)blockIdx.x * NH * DD);
        #pragma unroll
        for (int j = 0; j < 3; ++j) {
            float4 v0 = scr[(0*4 + h) * C4 + j * 64 + ln];
            float4 v1 = scr[(1*4 + h) * C4 + j * 64 + ln];
            float4 v2 = scr[(2*4 + h) * C4 + j * 64 + ln];
            float4 v3 = scr[(3*4 + h) * C4 + j * 64 + ln];
            float4 v;
            v.x = w0*v0.x + w1*v1.x + w2*v2.x + w3*v3.x;
            v.y = w0*v0.y + w1*v1.y + w2*v2.y + w3*v3.y;
            v.z = w0*v0.z + w1*v1.z + w2*v2.z + w3*v3.z;
            v.w = w0*v0.w + w1*v1.w + w2*v2.w + w3*v3.w;
            mo[h * C4 + j * 64 + ln] = v;
        }
        if (tid < NH) {
            int hh = tid;
            float Mh = fmaxf(fmaxf(mls[0][hh*2], mls[1][hh*2]), fmaxf(mls[2][hh*2], mls[3][hh*2]));
            float Lh = __expf(mls[0][hh*2] - Mh) * mls[0][hh*2+1]
                     + __expf(mls[1][hh*2] - Mh) * mls[1][hh*2+1]
                     + __expf(mls[2][hh*2] - Mh) * mls[2][hh*2+1]
                     + __expf(mls[3][hh*2] - Mh) * mls[3][hh*2+1];
            float* mp = ml + (size_t)blockIdx.x * NH * 2;
            mp[hh * 2 + 0] = Mh; mp[hh * 2 + 1] = Lh;
        }
    }
}

// ---------------- kT: transpose proj_w ----------------
__global__ __launch_bounds__(256) void kT(const float* __restrict__ pw,
                                          float* __restrict__ pwT) {
    int o = blockIdx.x * 256 + threadIdx.x;
    int j = o / INPROJ, i = o % INPROJ;
    pwT[(size_t)i * HIDDEN + j] = pw[o];
}

// ---------------- kComb: hbar = (1/L) * sum_ch w_ch * macc (384 blocks) ----------------
__global__ __launch_bounds__(256) void kComb(const float* __restrict__ macc,
                                             const float* __restrict__ ml,
                                             float* __restrict__ hbar) {
    int blk = blockIdx.x;
    int b = blk / 12, rem = blk % 12, h = rem / 3, dseg = rem % 3;
    int d = dseg * 256 + threadIdx.x;
    const float* mlb = ml + (size_t)b * NCH * 8 + h * 2;
    float M = -3.0e38f;
    #pragma unroll 8
    for (int c = 0; c < NCH; ++c) M = fmaxf(M, mlb[(size_t)c * 8]);
    float L = 0.f;
    #pragma unroll 8
    for (int c = 0; c < NCH; ++c)
        L += __expf(mlb[(size_t)c * 8] - M) * mlb[(size_t)c * 8 + 1];
    float acc = 0.f;
    const float* mc = macc + ((size_t)b * NCH * NH + h) * DD + d;
    #pragma unroll 8
    for (int c = 0; c < NCH; ++c)
        acc += __expf(mlb[(size_t)c * 8] - M) * mc[(size_t)c * NH * DD];
    hbar[((size_t)b * NH + h) * DD + d] = acc / L;
}

// ---------------- kC2: c = hbar*WV -> R[:,768:1024]; pooled -> R[:,1024:] ----------------
__global__ __launch_bounds__(256) void kC2(const float* __restrict__ hbar,
                                           const float* __restrict__ WV,
                                           const float* __restrict__ pooled,
                                           float* __restrict__ R) {
    int b = blockIdx.x;
    int h = threadIdx.x >> 6, v = threadIdx.x & 63;
    const float* hb = hbar + ((size_t)b * NH + h) * DD;
    const float* wv = WV + (size_t)h * DD * 64 + v;
    float acc = 0.f;
    #pragma unroll 8
    for (int d = 0; d < DD; ++d) acc += hb[d] * wv[(size_t)d * 64];
    R[(size_t)b * INPROJ + DD + threadIdx.x] = acc;
    for (int i = threadIdx.x; i < DD; i += 256)
        R[(size_t)b * INPROJ + DD + 256 + i] = pooled[(size_t)b * DD + i];
}

// ---------------- kH1: partial hidden GEMM, 7-way split over INPROJ ----------------
__global__ __launch_bounds__(256) void kH1(const float* __restrict__ R,
                                           const float* __restrict__ pwT,
                                           float* __restrict__ part2) {
    int b = blockIdx.x / 7, seg = blockIdx.x % 7;
    int j = threadIdx.x;
    __shared__ float r_s[256];
    r_s[j] = R[(size_t)b * INPROJ + seg * 256 + j];
    __syncthreads();
    float acc = 0.f;
    const float* pT = pwT + (size_t)seg * 256 * HIDDEN + j;
    #pragma unroll 8
    for (int i = 0; i < 256; ++i) acc += r_s[i] * pT[(size_t)i * HIDDEN];
    part2[((size_t)b * 7 + seg) * HIDDEN + j] = acc;
}

// ---------------- kH2: reduce partials + GELU + logits ----------------
__global__ __launch_bounds__(256) void kH2(const float* __restrict__ part2,
                                           const float* __restrict__ pb,
                                           const float* __restrict__ mw,
                                           const float* __restrict__ mb,
                                           float* __restrict__ out) {
    int b = blockIdx.x, j = threadIdx.x;
    float acc = pb[j];
    #pragma unroll
    for (int s = 0; s < 7; ++s) acc += part2[((size_t)b * 7 + s) * HIDDEN + j];
    float hdn = 0.5f * acc * (1.f + erff(acc * 0.70710678118654752f));
    float p0 = hdn * mw[j];
    float p1 = hdn * mw[HIDDEN + j];
    #pragma unroll
    for (int off = 32; off; off >>= 1) {
        p0 += __shfl_xor(p0, off);
        p1 += __shfl_xor(p1, off);
    }
    __shared__ float r0[4], r1[4];
    if ((j & 63) == 0) {
        r0[j >> 6] = p0;
        r1[j >> 6] = p1;
    }
    __syncthreads();
    if (j == 0) {
        out[b * 2 + 0] = r0[0] + r0[1] + r0[2] + r0[3] + mb[0];
        out[b * 2 + 1] = r1[0] + r1[1] + r1[2] + r1[3] + mb[1];
    }
}

extern "C" void kernel_launch(void* const* d_in, const int* in_sizes, int n_in,
                              void* d_out, int out_size, void* d_ws, size_t ws_size,
                              hipStream_t stream) {
    const float* H      = (const float*)d_in[0];
    const int*   mask   = (const int*)d_in[1];
    const int*   noun   = (const int*)d_in[2];
    const float* pooled = (const float*)d_in[3];
    const float* WQ     = (const float*)d_in[4];
    const float* WK     = (const float*)d_in[5];
    const float* WV     = (const float*)d_in[6];
    const float* relb   = (const float*)d_in[7];
    const float* pw     = (const float*)d_in[8];
    const float* pb     = (const float*)d_in[9];
    const float* mw     = (const float*)d_in[10];
    const float* mb     = (const float*)d_in[11];
    float* out = (float*)d_out;

    float* ws    = (float*)d_ws;
    float* R     = ws;                                // BB*INPROJ     = 57344
    float* qk    = R + (size_t)BB * INPROJ;           // BB*NH*DD      = 98304
    float* macc  = qk + (size_t)BB * NH * DD;         // BB*NCH*NH*DD  = 3145728
    float* ml    = macc + (size_t)BB * NCH * NH * DD; // BB*NCH*NH*2   = 8192
    float* hbar  = ml + (size_t)BB * NCH * NH * 2;    // BB*NH*DD      = 98304
    float* pwT   = hbar + (size_t)BB * NH * DD;       // INPROJ*HIDDEN = 458752
    float* part2 = pwT + (size_t)INPROJ * HIDDEN;     // BB*7*HIDDEN   = 57344

    kA<<<BB * NH, 256, 0, stream>>>(H, noun, WQ, WK, R, qk);
    kT<<<(HIDDEN * INPROJ) / 256, 256, 0, stream>>>(pw, pwT);
    kFlash<<<BB * NCH, 256, 0, stream>>>(H, mask, noun, relb, qk, macc, ml);
    kComb<<<BB * 12, 256, 0, stream>>>(macc, ml, hbar);
    kC2<<<BB, 256, 0, stream>>>(hbar, WV, pooled, R);
    kH1<<<BB * 7, 256, 0, stream>>>(R, pwT, part2);
    kH2<<<BB, 256, 0, stream>>>(part2, pb, mw, mb, out);
}